// Round 5
// baseline (526.595 us; speedup 1.0000x reference)
//
#include <hip/hip_runtime.h>

#define NE 8
#define HW 128
#define OUT_HW 384
#define C1 64
#define C2 32
#define C3 9

typedef __attribute__((ext_vector_type(4))) float f32x4;
typedef __attribute__((ext_vector_type(8))) short bf16x8s;

// Prepacked conv2 weights, bf16: [e][koff(ky*3+kx)][oc=32][ic=64]
__device__ __align__(16) unsigned short g_w2b[NE * 9 * C2 * C1];
// Prepacked conv3 weights, bf16: [e][koff][oc=16 (9 valid)][ic=32]
__device__ __align__(16) unsigned short g_w3b[NE * 9 * 16 * 32];

__device__ __forceinline__ unsigned short f2bf(float f) {
    unsigned u = __builtin_bit_cast(unsigned, f);
    u += 0x7fffu + ((u >> 16) & 1u);          // round-nearest-even
    return (unsigned short)(u >> 16);
}

__global__ void repack_weights_kernel(const float* __restrict__ w2,
                                      const float* __restrict__ w3) {
    int i = blockIdx.x * 256 + threadIdx.x;
    const int n2 = NE * C2 * C1 * 9;          // 36864
    const int n3 = NE * 9 * 16 * 32;          // 36864
    if (i < n2) {
        // source: [e][oc][ic][ky][kx] -> dest [e][koff][oc][ic]
        int e = i / (C2 * C1 * 9);
        int r = i - e * (C2 * C1 * 9);
        int oc = r / (C1 * 9); r -= oc * (C1 * 9);
        int ic = r / 9;
        int koff = r - ic * 9;
        g_w2b[((e * 9 + koff) * C2 + oc) * C1 + ic] = f2bf(w2[i]);
    } else if (i < n2 + n3) {
        int j = i - n2;
        int e = j / (9 * 16 * 32);
        int r = j - e * (9 * 16 * 32);
        int koff = r / 512; r -= koff * 512;
        int oc = r / 32;
        int ic = r - oc * 32;
        float v = 0.f;
        if (oc < C3) v = w3[((e * C3 + oc) * 32 + ic) * 9 + koff];
        g_w3b[((e * 9 + koff) * 16 + oc) * 32 + ic] = f2bf(v);
    }
}

__device__ __forceinline__ float fast_tanh(float x) {
    float ax = fabsf(x);
    float ex = __expf(2.0f * ax);                       // inf-safe
    float tv = 1.0f - 2.0f * __builtin_amdgcn_rcpf(ex + 1.0f);
    return copysignf(tv, x);
}

__launch_bounds__(256, 6)
__global__ void espcn_fused_kernel(const float* __restrict__ x,
                                   const int* __restrict__ ci,
                                   const float* __restrict__ w1,
                                   const float* __restrict__ b1,
                                   const float* __restrict__ b2,
                                   const float* __restrict__ b3,
                                   float* __restrict__ out) {
    __shared__ float xs[16][17];                            // x patch
    __shared__ __align__(16) unsigned short h1s[144 * 64];  // [pixel][ic] bf16, XOR-swizzled (128B rows)
    __shared__ __align__(16) unsigned short h2b[100 * 32];  // [pixel][ic] bf16, XOR-swizzled (64B rows)
    // phase-3 output staging tile, aliased over h1s (dead by then): 24 x 28 floats
    float (*outT)[28] = (float(*)[28])h1s;                  // 2688 B << 18432 B

    const int tx = blockIdx.x, ty = blockIdx.y, b = blockIdx.z;
    const int R0 = ty * 8, C0 = tx * 8;
    int e = ci[b];
    e = __builtin_amdgcn_readfirstlane(e);                  // force SGPR: scalar weight loads
    const int t = threadIdx.x;
    const int lane = t & 63, wave = t >> 6;

    // ---- phase 0: stage x patch rows [R0-4, R0+12), cols [C0-4, C0+12) ----
    {
        int i = t >> 4, j = t & 15;
        int gy = R0 - 4 + i, gx = C0 - 4 + j;
        float v = 0.f;
        if (gy >= 0 && gy < HW && gx >= 0 && gx < HW)
            v = x[(b * HW + gy) * HW + gx];
        xs[i][j] = v;
    }
    __syncthreads();

    // ---- phase 1: conv1 (5x5, 1->64) + tanh -> h1s[pixel][ic] bf16 ----
    // 768 tasks = 64 channels x 12 columns; 3 tasks per thread.
    {
        const float* w1e = w1 + e * C1 * 25;
        const float* b1e = b1 + e * C1;
        #pragma unroll
        for (int it = 0; it < 3; ++it) {
            int task = it * 256 + t;
            int c = task / 12, j = task - c * 12;
            float wreg[25];
            #pragma unroll
            for (int q = 0; q < 25; ++q) wreg[q] = w1e[c * 25 + q];
            float bias = b1e[c];
            float acc[12];
            #pragma unroll
            for (int r = 0; r < 12; ++r) acc[r] = bias;
            #pragma unroll
            for (int i = 0; i < 16; ++i) {
                float v0 = xs[i][j], v1 = xs[i][j + 1], v2 = xs[i][j + 2],
                      v3 = xs[i][j + 3], v4 = xs[i][j + 4];
                #pragma unroll
                for (int dy = 0; dy < 5; ++dy) {
                    int r = i - dy;
                    if (r >= 0 && r < 12) {
                        acc[r] = fmaf(v0, wreg[dy * 5 + 0], acc[r]);
                        acc[r] = fmaf(v1, wreg[dy * 5 + 1], acc[r]);
                        acc[r] = fmaf(v2, wreg[dy * 5 + 2], acc[r]);
                        acc[r] = fmaf(v3, wreg[dy * 5 + 3], acc[r]);
                        acc[r] = fmaf(v4, wreg[dy * 5 + 4], acc[r]);
                    }
                }
            }
            #pragma unroll
            for (int r = 0; r < 12; ++r) {
                int gy = R0 - 2 + r, gx = C0 - 2 + j;
                float val = (gy >= 0 && gy < HW && gx >= 0 && gx < HW) ? fast_tanh(acc[r]) : 0.f;
                int p = r * 12 + j;
                int off = ((p << 7) + (c << 1)) ^ ((p & 7) << 4);
                *(unsigned short*)((char*)h1s + off) = f2bf(val);
            }
        }
    }
    __syncthreads();

    // ---- phase 2: conv2 (3x3, 64->32) as bf16 MFMA + tanh -> h2b bf16 ----
    // M = 100 pixels (8 tiles of 16, padded), N = 32 oc (2 tiles), K = 576 (18 steps of 32).
    {
        const unsigned short* w2e = g_w2b + e * 9 * C2 * C1;
        const int g = lane >> 4, r16 = lane & 15;
        int ps0 = wave * 32 + r16;       if (ps0 > 99) ps0 = 99;
        int ps1 = wave * 32 + 16 + r16;  if (ps1 > 99) ps1 = 99;
        const int ab0 = (ps0 / 10) * 12 + (ps0 % 10);
        const int ab1 = (ps1 / 10) * 12 + (ps1 % 10);
        f32x4 acc00 = {0.f, 0.f, 0.f, 0.f}, acc01 = {0.f, 0.f, 0.f, 0.f};
        f32x4 acc10 = {0.f, 0.f, 0.f, 0.f}, acc11 = {0.f, 0.f, 0.f, 0.f};
        const int laneB = (r16 * C1 + g * 8);          // elements
        #pragma unroll
        for (int s = 0; s < 18; ++s) {
            const int koff = s >> 1;
            const int drow = (koff / 3) * 12 + (koff % 3);
            const int icoff2 = ((s & 1) * 32 + g * 8) * 2;
            int r0 = ab0 + drow, r1 = ab1 + drow;
            int o0 = ((r0 << 7) + icoff2) ^ ((r0 & 7) << 4);
            int o1 = ((r1 << 7) + icoff2) ^ ((r1 & 7) << 4);
            bf16x8s A0 = *(const bf16x8s*)((const char*)h1s + o0);
            bf16x8s A1 = *(const bf16x8s*)((const char*)h1s + o1);
            const unsigned short* wp = w2e + koff * C2 * C1 + (s & 1) * 32;
            bf16x8s B0 = *(const bf16x8s*)(wp + laneB);
            bf16x8s B1 = *(const bf16x8s*)(wp + 16 * C1 + laneB);
            acc00 = __builtin_amdgcn_mfma_f32_16x16x32_bf16(A0, B0, acc00, 0, 0, 0);
            acc01 = __builtin_amdgcn_mfma_f32_16x16x32_bf16(A0, B1, acc01, 0, 0, 0);
            acc10 = __builtin_amdgcn_mfma_f32_16x16x32_bf16(A1, B0, acc10, 0, 0, 0);
            acc11 = __builtin_amdgcn_mfma_f32_16x16x32_bf16(A1, B1, acc11, 0, 0, 0);
        }
        // epilogue: D row = (lane>>4)*4 + reg (pixel), col = lane&15 (oc)
        const float* b2e = b2 + e * C2;
        float bias0 = b2e[r16], bias1 = b2e[16 + r16];
        #pragma unroll
        for (int m = 0; m < 2; ++m) {
            f32x4 aN0 = m ? acc10 : acc00;
            f32x4 aN1 = m ? acc11 : acc01;
            int mtbase = wave * 32 + m * 16;
            #pragma unroll
            for (int q = 0; q < 4; ++q) {
                int pd = mtbase + g * 4 + q;
                if (pd < 100) {
                    int y = pd / 10, xq2 = pd - y * 10;
                    int gy = R0 - 1 + y, gx = C0 - 1 + xq2;
                    bool inimg = (gy >= 0 && gy < HW && gx >= 0 && gx < HW);
                    float v0 = inimg ? fast_tanh(aN0[q] + bias0) : 0.f;
                    float v1 = inimg ? fast_tanh(aN1[q] + bias1) : 0.f;
                    int swz = (pd & 3) << 4;
                    int off0 = (pd << 6) + ((2 * r16) ^ swz);
                    int off1 = (pd << 6) + ((2 * r16 + 32) ^ swz);
                    *(unsigned short*)((char*)h2b + off0) = f2bf(v0);
                    *(unsigned short*)((char*)h2b + off1) = f2bf(v1);
                }
            }
        }
    }
    __syncthreads();

    // ---- phase 3: conv3 (3x3, 32->9 pad 16) as bf16 MFMA -> LDS out tile ----
    // M = 64 output pixels (4 tiles, one per wave), N = 16 (9 valid), K = 288 (9 steps).
    {
        const unsigned short* w3e = g_w3b + e * 9 * 16 * 32;
        const int g = lane >> 4, r16 = lane & 15;
        const int pxA = wave * 16 + r16;            // A-row pixel
        const int oyA = pxA >> 3, oxA = pxA & 7;
        f32x4 acc = {0.f, 0.f, 0.f, 0.f};
        #pragma unroll
        for (int s = 0; s < 9; ++s) {
            const int ky = s / 3, kx = s % 3;
            int p = (oyA + ky) * 10 + (oxA + kx);
            int offA = (p << 6) + ((g * 16) ^ ((p & 3) << 4));
            bf16x8s A = *(const bf16x8s*)((const char*)h2b + offA);
            bf16x8s B = *(const bf16x8s*)(w3e + (s * 16 + r16) * 32 + g * 8);
            acc = __builtin_amdgcn_mfma_f32_16x16x32_bf16(A, B, acc, 0, 0, 0);
        }
        // D: row (pixel-in-tile) = g*4+q, col (oc) = r16.  Stage into LDS tile.
        if (r16 < C3) {
            float bias = b3[e * C3 + r16];
            #pragma unroll
            for (int q = 0; q < 4; ++q) {
                int pxd = wave * 16 + g * 4 + q;
                int oyd = pxd >> 3, oxd = pxd & 7;
                outT[oyd * 3 + r16 / 3][oxd * 3 + r16 % 3] = acc[q] + bias;
            }
        }
    }
    __syncthreads();

    // ---- phase 4: coalesced output write: 24 rows x 6 float4 (96 B/row) ----
    if (t < 144) {
        int row = t / 6, c4 = t - row * 6;
        f32x4 v = *(const f32x4*)&outT[row][c4 * 4];
        int gr = R0 * 3 + row;              // 24*ty + row
        int gc = C0 * 3 + c4 * 4;           // 24*tx + 4*c4
        *(f32x4*)&out[(b * OUT_HW + gr) * OUT_HW + gc] = v;
    }
}

extern "C" void kernel_launch(void* const* d_in, const int* in_sizes, int n_in,
                              void* d_out, int out_size, void* d_ws, size_t ws_size,
                              hipStream_t stream) {
    const float* x  = (const float*)d_in[0];
    const int*   ci = (const int*)  d_in[1];
    const float* w1 = (const float*)d_in[2];
    const float* b1 = (const float*)d_in[3];
    const float* w2 = (const float*)d_in[4];
    const float* b2 = (const float*)d_in[5];
    const float* w3 = (const float*)d_in[6];
    const float* b3 = (const float*)d_in[7];
    float* out = (float*)d_out;

    {
        const int total = NE * C2 * C1 * 9 + NE * 9 * 16 * 32;
        repack_weights_kernel<<<(total + 255) / 256, 256, 0, stream>>>(w2, w3);
    }
    {
        dim3 grid(HW / 8, HW / 8, 32);
        espcn_fused_kernel<<<grid, 256, 0, stream>>>(x, ci, w1, b1, b2, b3, out);
    }
}

// Round 6
// 254.507 us; speedup vs baseline: 2.0691x; 2.0691x over previous
//
#include <hip/hip_runtime.h>

#define NE 8
#define HW 128
#define OUT_HW 384
#define C1 64
#define C2 32
#define C3 9

typedef __attribute__((ext_vector_type(4))) float f32x4;
typedef __attribute__((ext_vector_type(8))) short bf16x8s;

// Prepacked conv2 weights, bf16: [e][koff(ky*3+kx)][oc=32][ic=64]
__device__ __align__(16) unsigned short g_w2b[NE * 9 * C2 * C1];
// Prepacked conv3 weights, bf16: [e][koff][oc=16 (9 valid)][ic=32]
__device__ __align__(16) unsigned short g_w3b[NE * 9 * 16 * 32];

__device__ __forceinline__ unsigned short f2bf(float f) {
    unsigned u = __builtin_bit_cast(unsigned, f);
    u += 0x7fffu + ((u >> 16) & 1u);          // round-nearest-even
    return (unsigned short)(u >> 16);
}

__global__ void repack_weights_kernel(const float* __restrict__ w2,
                                      const float* __restrict__ w3) {
    int i = blockIdx.x * 256 + threadIdx.x;
    const int n2 = NE * C2 * C1 * 9;          // 36864
    const int n3 = NE * 9 * 16 * 32;          // 36864
    if (i < n2) {
        // source: [e][oc][ic][ky][kx] -> dest [e][koff][oc][ic]
        int e = i / (C2 * C1 * 9);
        int r = i - e * (C2 * C1 * 9);
        int oc = r / (C1 * 9); r -= oc * (C1 * 9);
        int ic = r / 9;
        int koff = r - ic * 9;
        g_w2b[((e * 9 + koff) * C2 + oc) * C1 + ic] = f2bf(w2[i]);
    } else if (i < n2 + n3) {
        int j = i - n2;
        int e = j / (9 * 16 * 32);
        int r = j - e * (9 * 16 * 32);
        int koff = r / 512; r -= koff * 512;
        int oc = r / 32;
        int ic = r - oc * 32;
        float v = 0.f;
        if (oc < C3) v = w3[((e * C3 + oc) * 32 + ic) * 9 + koff];
        g_w3b[((e * 9 + koff) * 16 + oc) * 32 + ic] = f2bf(v);
    }
}

__device__ __forceinline__ float fast_tanh(float x) {
    float ax = fabsf(x);
    float ex = __expf(2.0f * ax);                       // inf-safe
    float tv = 1.0f - 2.0f * __builtin_amdgcn_rcpf(ex + 1.0f);
    return copysignf(tv, x);
}

__launch_bounds__(256, 4)
__global__ void espcn_fused_kernel(const float* __restrict__ x,
                                   const int* __restrict__ ci,
                                   const float* __restrict__ w1,
                                   const float* __restrict__ b1,
                                   const float* __restrict__ b2,
                                   const float* __restrict__ b3,
                                   float* __restrict__ out) {
    __shared__ float xs[16][17];                            // x patch
    __shared__ __align__(16) unsigned short h1s[144 * 64];  // [pixel][ic] bf16, XOR-swizzled (128B rows)
    __shared__ __align__(16) unsigned short h2b[100 * 32];  // [pixel][ic] bf16, XOR-swizzled (64B rows)
    // phase-3 output staging tile, aliased over h1s (dead by then): 24 x 28 floats
    float (*outT)[28] = (float(*)[28])h1s;                  // 2688 B << 18432 B

    const int tx = blockIdx.x, ty = blockIdx.y, b = blockIdx.z;
    const int R0 = ty * 8, C0 = tx * 8;
    int e = ci[b];
    e = __builtin_amdgcn_readfirstlane(e);                  // force SGPR: scalar weight loads
    const int t = threadIdx.x;
    const int lane = t & 63, wave = t >> 6;

    // ---- phase 0: stage x patch rows [R0-4, R0+12), cols [C0-4, C0+12) ----
    {
        int i = t >> 4, j = t & 15;
        int gy = R0 - 4 + i, gx = C0 - 4 + j;
        float v = 0.f;
        if (gy >= 0 && gy < HW && gx >= 0 && gx < HW)
            v = x[(b * HW + gy) * HW + gx];
        xs[i][j] = v;
    }
    __syncthreads();

    // ---- phase 1: conv1 (5x5, 1->64) + tanh -> h1s[pixel][ic] bf16 ----
    // 768 tasks = 64 channels x 12 columns; 3 tasks per thread.
    {
        const float* w1e = w1 + e * C1 * 25;
        const float* b1e = b1 + e * C1;
        #pragma unroll
        for (int it = 0; it < 3; ++it) {
            int task = it * 256 + t;
            int c = task / 12, j = task - c * 12;
            float wreg[25];
            #pragma unroll
            for (int q = 0; q < 25; ++q) wreg[q] = w1e[c * 25 + q];
            float bias = b1e[c];
            float acc[12];
            #pragma unroll
            for (int r = 0; r < 12; ++r) acc[r] = bias;
            #pragma unroll
            for (int i = 0; i < 16; ++i) {
                float v0 = xs[i][j], v1 = xs[i][j + 1], v2 = xs[i][j + 2],
                      v3 = xs[i][j + 3], v4 = xs[i][j + 4];
                #pragma unroll
                for (int dy = 0; dy < 5; ++dy) {
                    int r = i - dy;
                    if (r >= 0 && r < 12) {
                        acc[r] = fmaf(v0, wreg[dy * 5 + 0], acc[r]);
                        acc[r] = fmaf(v1, wreg[dy * 5 + 1], acc[r]);
                        acc[r] = fmaf(v2, wreg[dy * 5 + 2], acc[r]);
                        acc[r] = fmaf(v3, wreg[dy * 5 + 3], acc[r]);
                        acc[r] = fmaf(v4, wreg[dy * 5 + 4], acc[r]);
                    }
                }
            }
            #pragma unroll
            for (int r = 0; r < 12; ++r) {
                int gy = R0 - 2 + r, gx = C0 - 2 + j;
                float val = (gy >= 0 && gy < HW && gx >= 0 && gx < HW) ? fast_tanh(acc[r]) : 0.f;
                int p = r * 12 + j;
                int off = ((p << 7) + (c << 1)) ^ ((p & 7) << 4);
                *(unsigned short*)((char*)h1s + off) = f2bf(val);
            }
        }
    }
    __syncthreads();

    // ---- phase 2: conv2 (3x3, 64->32) as bf16 MFMA + tanh -> h2b bf16 ----
    // M = 100 pixels (8 tiles of 16, padded), N = 32 oc (2 tiles), K = 576 (18 steps of 32).
    {
        const unsigned short* w2e = g_w2b + e * 9 * C2 * C1;
        const int g = lane >> 4, r16 = lane & 15;
        int ps0 = wave * 32 + r16;       if (ps0 > 99) ps0 = 99;
        int ps1 = wave * 32 + 16 + r16;  if (ps1 > 99) ps1 = 99;
        const int ab0 = (ps0 / 10) * 12 + (ps0 % 10);
        const int ab1 = (ps1 / 10) * 12 + (ps1 % 10);
        f32x4 acc00 = {0.f, 0.f, 0.f, 0.f}, acc01 = {0.f, 0.f, 0.f, 0.f};
        f32x4 acc10 = {0.f, 0.f, 0.f, 0.f}, acc11 = {0.f, 0.f, 0.f, 0.f};
        const int laneB = (r16 * C1 + g * 8);          // elements
        #pragma unroll
        for (int s = 0; s < 18; ++s) {
            const int koff = s >> 1;
            const int drow = (koff / 3) * 12 + (koff % 3);
            const int icoff2 = ((s & 1) * 32 + g * 8) * 2;
            int r0 = ab0 + drow, r1 = ab1 + drow;
            int o0 = ((r0 << 7) + icoff2) ^ ((r0 & 7) << 4);
            int o1 = ((r1 << 7) + icoff2) ^ ((r1 & 7) << 4);
            bf16x8s A0 = *(const bf16x8s*)((const char*)h1s + o0);
            bf16x8s A1 = *(const bf16x8s*)((const char*)h1s + o1);
            const unsigned short* wp = w2e + koff * C2 * C1 + (s & 1) * 32;
            bf16x8s B0 = *(const bf16x8s*)(wp + laneB);
            bf16x8s B1 = *(const bf16x8s*)(wp + 16 * C1 + laneB);
            acc00 = __builtin_amdgcn_mfma_f32_16x16x32_bf16(A0, B0, acc00, 0, 0, 0);
            acc01 = __builtin_amdgcn_mfma_f32_16x16x32_bf16(A0, B1, acc01, 0, 0, 0);
            acc10 = __builtin_amdgcn_mfma_f32_16x16x32_bf16(A1, B0, acc10, 0, 0, 0);
            acc11 = __builtin_amdgcn_mfma_f32_16x16x32_bf16(A1, B1, acc11, 0, 0, 0);
        }
        // epilogue: D row = (lane>>4)*4 + reg (pixel), col = lane&15 (oc)
        const float* b2e = b2 + e * C2;
        float bias0 = b2e[r16], bias1 = b2e[16 + r16];
        #pragma unroll
        for (int m = 0; m < 2; ++m) {
            f32x4 aN0 = m ? acc10 : acc00;
            f32x4 aN1 = m ? acc11 : acc01;
            int mtbase = wave * 32 + m * 16;
            #pragma unroll
            for (int q = 0; q < 4; ++q) {
                int pd = mtbase + g * 4 + q;
                if (pd < 100) {
                    int y = pd / 10, xq2 = pd - y * 10;
                    int gy = R0 - 1 + y, gx = C0 - 1 + xq2;
                    bool inimg = (gy >= 0 && gy < HW && gx >= 0 && gx < HW);
                    float v0 = inimg ? fast_tanh(aN0[q] + bias0) : 0.f;
                    float v1 = inimg ? fast_tanh(aN1[q] + bias1) : 0.f;
                    int swz = (pd & 3) << 4;
                    int off0 = (pd << 6) + ((2 * r16) ^ swz);
                    int off1 = (pd << 6) + ((2 * r16 + 32) ^ swz);
                    *(unsigned short*)((char*)h2b + off0) = f2bf(v0);
                    *(unsigned short*)((char*)h2b + off1) = f2bf(v1);
                }
            }
        }
    }
    __syncthreads();

    // ---- phase 3: conv3 (3x3, 32->9 pad 16) as bf16 MFMA -> LDS out tile ----
    // M = 64 output pixels (4 tiles, one per wave), N = 16 (9 valid), K = 288 (9 steps).
    {
        const unsigned short* w3e = g_w3b + e * 9 * 16 * 32;
        const int g = lane >> 4, r16 = lane & 15;
        const int pxA = wave * 16 + r16;            // A-row pixel
        const int oyA = pxA >> 3, oxA = pxA & 7;
        f32x4 acc = {0.f, 0.f, 0.f, 0.f};
        #pragma unroll
        for (int s = 0; s < 9; ++s) {
            const int ky = s / 3, kx = s % 3;
            int p = (oyA + ky) * 10 + (oxA + kx);
            int offA = (p << 6) + ((g * 16) ^ ((p & 3) << 4));
            bf16x8s A = *(const bf16x8s*)((const char*)h2b + offA);
            bf16x8s B = *(const bf16x8s*)(w3e + (s * 16 + r16) * 32 + g * 8);
            acc = __builtin_amdgcn_mfma_f32_16x16x32_bf16(A, B, acc, 0, 0, 0);
        }
        // D: row (pixel-in-tile) = g*4+q, col (oc) = r16.  Stage into LDS tile.
        if (r16 < C3) {
            float bias = b3[e * C3 + r16];
            #pragma unroll
            for (int q = 0; q < 4; ++q) {
                int pxd = wave * 16 + g * 4 + q;
                int oyd = pxd >> 3, oxd = pxd & 7;
                outT[oyd * 3 + r16 / 3][oxd * 3 + r16 % 3] = acc[q] + bias;
            }
        }
    }
    __syncthreads();

    // ---- phase 4: coalesced output write: 24 rows x 6 float4 (96 B/row) ----
    if (t < 144) {
        int row = t / 6, c4 = t - row * 6;
        f32x4 v = *(const f32x4*)&outT[row][c4 * 4];
        int gr = R0 * 3 + row;              // 24*ty + row
        int gc = C0 * 3 + c4 * 4;           // 24*tx + 4*c4
        *(f32x4*)&out[(b * OUT_HW + gr) * OUT_HW + gc] = v;
    }
}

extern "C" void kernel_launch(void* const* d_in, const int* in_sizes, int n_in,
                              void* d_out, int out_size, void* d_ws, size_t ws_size,
                              hipStream_t stream) {
    const float* x  = (const float*)d_in[0];
    const int*   ci = (const int*)  d_in[1];
    const float* w1 = (const float*)d_in[2];
    const float* b1 = (const float*)d_in[3];
    const float* w2 = (const float*)d_in[4];
    const float* b2 = (const float*)d_in[5];
    const float* w3 = (const float*)d_in[6];
    const float* b3 = (const float*)d_in[7];
    float* out = (float*)d_out;

    {
        const int total = NE * C2 * C1 * 9 + NE * 9 * 16 * 32;
        repack_weights_kernel<<<(total + 255) / 256, 256, 0, stream>>>(w2, w3);
    }
    {
        dim3 grid(HW / 8, HW / 8, 32);
        espcn_fused_kernel<<<grid, 256, 0, stream>>>(x, ci, w1, b1, b2, b3, out);
    }
}

// Round 7
// 249.638 us; speedup vs baseline: 2.1094x; 1.0195x over previous
//
#include <hip/hip_runtime.h>

#define NE 8
#define HW 128
#define OUT_HW 384
#define C1 64
#define C2 32
#define C3 9

typedef __attribute__((ext_vector_type(4))) float f32x4;
typedef __attribute__((ext_vector_type(8))) short bf16x8s;

// Prepacked conv1 weights, bf16: [e][oc=64][tap=32 (25 valid, rest 0)]
__device__ __align__(16) unsigned short g_w1b[NE * C1 * 32];
// Prepacked conv2 weights, bf16: [e][koff(ky*3+kx)][oc=32][ic=64]
__device__ __align__(16) unsigned short g_w2b[NE * 9 * C2 * C1];
// Prepacked conv3 weights, bf16: [e][koff][oc=16 (9 valid)][ic=32]
__device__ __align__(16) unsigned short g_w3b[NE * 9 * 16 * 32];

__device__ __forceinline__ unsigned short f2bf(float f) {
    unsigned u = __builtin_bit_cast(unsigned, f);
    u += 0x7fffu + ((u >> 16) & 1u);          // round-nearest-even
    return (unsigned short)(u >> 16);
}

__global__ void repack_weights_kernel(const float* __restrict__ w1,
                                      const float* __restrict__ w2,
                                      const float* __restrict__ w3) {
    int i = blockIdx.x * 256 + threadIdx.x;
    const int n2 = NE * C2 * C1 * 9;          // 36864
    const int n1 = NE * C1 * 32;              // 16384
    const int n3 = NE * 9 * 16 * 32;          // 36864
    if (i < n2) {
        // source: [e][oc][ic][ky][kx] -> dest [e][koff][oc][ic]
        int e = i / (C2 * C1 * 9);
        int r = i - e * (C2 * C1 * 9);
        int oc = r / (C1 * 9); r -= oc * (C1 * 9);
        int ic = r / 9;
        int koff = r - ic * 9;
        g_w2b[((e * 9 + koff) * C2 + oc) * C1 + ic] = f2bf(w2[i]);
    } else if (i < n2 + n1) {
        int j = i - n2;                        // [e][oc][tap]
        int tap = j & 31;
        int eoc = j >> 5;                      // e*64+oc
        float v = (tap < 25) ? w1[eoc * 25 + tap] : 0.f;
        g_w1b[j] = f2bf(v);
    } else if (i < n2 + n1 + n3) {
        int j = i - n2 - n1;
        int e = j / (9 * 16 * 32);
        int r = j - e * (9 * 16 * 32);
        int koff = r / 512; r -= koff * 512;
        int oc = r / 32;
        int ic = r - oc * 32;
        float v = 0.f;
        if (oc < C3) v = w3[((e * C3 + oc) * 32 + ic) * 9 + koff];
        g_w3b[((e * 9 + koff) * 16 + oc) * 32 + ic] = f2bf(v);
    }
}

__device__ __forceinline__ float fast_tanh(float x) {
    float ax = fabsf(x);
    float ex = __expf(2.0f * ax);                       // inf-safe
    float tv = 1.0f - 2.0f * __builtin_amdgcn_rcpf(ex + 1.0f);
    return copysignf(tv, x);
}

__launch_bounds__(256, 4)
__global__ void espcn_fused_kernel(const float* __restrict__ x,
                                   const int* __restrict__ ci,
                                   const float* __restrict__ b1,
                                   const float* __restrict__ b2,
                                   const float* __restrict__ b3,
                                   float* __restrict__ out) {
    __shared__ float xs[16][17];                            // x patch
    __shared__ __align__(16) unsigned short imc[144 * 40];  // im2col [px][tap], 80B row stride
    __shared__ __align__(16) unsigned short h1s[144 * 64];  // [pixel][ic] bf16, XOR-swizzled (128B rows)
    __shared__ __align__(16) unsigned short h2b[100 * 32];  // [pixel][ic] bf16, XOR-swizzled (64B rows)
    // phase-3 output staging tile, aliased over h1s (dead by then): 24 x 28 floats
    float (*outT)[28] = (float(*)[28])h1s;                  // 2688 B << 18432 B

    const int tx = blockIdx.x, ty = blockIdx.y, b = blockIdx.z;
    const int R0 = ty * 8, C0 = tx * 8;
    int e = ci[b];
    e = __builtin_amdgcn_readfirstlane(e);                  // force SGPR: scalar weight loads
    const int t = threadIdx.x;
    const int lane = t & 63, wave = t >> 6;
    const int g = lane >> 4, r16 = lane & 15;

    // ---- phase 0: stage x patch rows [R0-4, R0+12), cols [C0-4, C0+12) ----
    {
        int i = t >> 4, j = t & 15;
        int gy = R0 - 4 + i, gx = C0 - 4 + j;
        float v = 0.f;
        if (gy >= 0 && gy < HW && gx >= 0 && gx < HW)
            v = x[(b * HW + gy) * HW + gx];
        xs[i][j] = v;
    }
    __syncthreads();

    // ---- phase 0.5: build im2col: 144 px x 16 tap-pairs (u32 writes) ----
    {
        #pragma unroll
        for (int q = 0; q < 9; ++q) {
            int idx = q * 256 + t;             // [0, 2304)
            int p = idx >> 4, w = idx & 15;
            int i = p / 12, j = p - i * 12;
            int tap0 = 2 * w, tap1 = 2 * w + 1;
            unsigned short lo = 0, hi = 0;
            if (tap0 < 25) lo = f2bf(xs[i + tap0 / 5][j + tap0 % 5]);
            if (tap1 < 25) hi = f2bf(xs[i + tap1 / 5][j + tap1 % 5]);
            *(unsigned*)((char*)imc + p * 80 + w * 4) = (unsigned)lo | ((unsigned)hi << 16);
        }
    }
    __syncthreads();

    // ---- phase 1: conv1 as MFMA (M=144 px, N=64 oc, K=32) + tanh -> h1s ----
    // 9 M-tiles x 4 N-tiles (one per wave) x 1 K-step.
    {
        const unsigned short* w1e = g_w1b + e * C1 * 32;
        const int oc = wave * 16 + r16;
        bf16x8s B = *(const bf16x8s*)(w1e + oc * 32 + g * 8);
        float bias = b1[e * C1 + oc];
        #pragma unroll
        for (int mt = 0; mt < 9; ++mt) {
            bf16x8s A = *(const bf16x8s*)((const char*)imc + (mt * 16 + r16) * 80 + g * 16);
            f32x4 acc = {0.f, 0.f, 0.f, 0.f};
            acc = __builtin_amdgcn_mfma_f32_16x16x32_bf16(A, B, acc, 0, 0, 0);
            #pragma unroll
            for (int qq = 0; qq < 4; ++qq) {
                int p = mt * 16 + g * 4 + qq;
                int r = p / 12, jj = p - r * 12;
                int gy = R0 - 2 + r, gx = C0 - 2 + jj;
                float val = (gy >= 0 && gy < HW && gx >= 0 && gx < HW)
                            ? fast_tanh(acc[qq] + bias) : 0.f;
                int off = ((p << 7) + (oc << 1)) ^ ((p & 7) << 4);
                *(unsigned short*)((char*)h1s + off) = f2bf(val);
            }
        }
    }
    __syncthreads();

    // ---- phase 2: conv2 (3x3, 64->32) as bf16 MFMA + tanh -> h2b bf16 ----
    // M = 100 pixels (8 tiles of 16, padded), N = 32 oc (2 tiles), K = 576 (18 steps of 32).
    {
        const unsigned short* w2e = g_w2b + e * 9 * C2 * C1;
        int ps0 = wave * 32 + r16;       if (ps0 > 99) ps0 = 99;
        int ps1 = wave * 32 + 16 + r16;  if (ps1 > 99) ps1 = 99;
        const int ab0 = (ps0 / 10) * 12 + (ps0 % 10);
        const int ab1 = (ps1 / 10) * 12 + (ps1 % 10);
        f32x4 acc00 = {0.f, 0.f, 0.f, 0.f}, acc01 = {0.f, 0.f, 0.f, 0.f};
        f32x4 acc10 = {0.f, 0.f, 0.f, 0.f}, acc11 = {0.f, 0.f, 0.f, 0.f};
        const int laneB = (r16 * C1 + g * 8);          // elements
        #pragma unroll
        for (int s = 0; s < 18; ++s) {
            const int koff = s >> 1;
            const int drow = (koff / 3) * 12 + (koff % 3);
            const int icoff2 = ((s & 1) * 32 + g * 8) * 2;
            int r0 = ab0 + drow, r1 = ab1 + drow;
            int o0 = ((r0 << 7) + icoff2) ^ ((r0 & 7) << 4);
            int o1 = ((r1 << 7) + icoff2) ^ ((r1 & 7) << 4);
            bf16x8s A0 = *(const bf16x8s*)((const char*)h1s + o0);
            bf16x8s A1 = *(const bf16x8s*)((const char*)h1s + o1);
            const unsigned short* wp = w2e + koff * C2 * C1 + (s & 1) * 32;
            bf16x8s B0 = *(const bf16x8s*)(wp + laneB);
            bf16x8s B1 = *(const bf16x8s*)(wp + 16 * C1 + laneB);
            acc00 = __builtin_amdgcn_mfma_f32_16x16x32_bf16(A0, B0, acc00, 0, 0, 0);
            acc01 = __builtin_amdgcn_mfma_f32_16x16x32_bf16(A0, B1, acc01, 0, 0, 0);
            acc10 = __builtin_amdgcn_mfma_f32_16x16x32_bf16(A1, B0, acc10, 0, 0, 0);
            acc11 = __builtin_amdgcn_mfma_f32_16x16x32_bf16(A1, B1, acc11, 0, 0, 0);
        }
        // epilogue: D row = (lane>>4)*4 + reg (pixel), col = lane&15 (oc)
        const float* b2e = b2 + e * C2;
        float bias0 = b2e[r16], bias1 = b2e[16 + r16];
        #pragma unroll
        for (int m = 0; m < 2; ++m) {
            f32x4 aN0 = m ? acc10 : acc00;
            f32x4 aN1 = m ? acc11 : acc01;
            int mtbase = wave * 32 + m * 16;
            #pragma unroll
            for (int q = 0; q < 4; ++q) {
                int pd = mtbase + g * 4 + q;
                if (pd < 100) {
                    int y = pd / 10, xq2 = pd - y * 10;
                    int gy = R0 - 1 + y, gx = C0 - 1 + xq2;
                    bool inimg = (gy >= 0 && gy < HW && gx >= 0 && gx < HW);
                    float v0 = inimg ? fast_tanh(aN0[q] + bias0) : 0.f;
                    float v1 = inimg ? fast_tanh(aN1[q] + bias1) : 0.f;
                    int swz = (pd & 3) << 4;
                    int off0 = (pd << 6) + ((2 * r16) ^ swz);
                    int off1 = (pd << 6) + ((2 * r16 + 32) ^ swz);
                    *(unsigned short*)((char*)h2b + off0) = f2bf(v0);
                    *(unsigned short*)((char*)h2b + off1) = f2bf(v1);
                }
            }
        }
    }
    __syncthreads();

    // ---- phase 3: conv3 (3x3, 32->9 pad 16) as bf16 MFMA -> LDS out tile ----
    // M = 64 output pixels (4 tiles, one per wave), N = 16 (9 valid), K = 288 (9 steps).
    {
        const unsigned short* w3e = g_w3b + e * 9 * 16 * 32;
        const int pxA = wave * 16 + r16;            // A-row pixel
        const int oyA = pxA >> 3, oxA = pxA & 7;
        f32x4 acc = {0.f, 0.f, 0.f, 0.f};
        #pragma unroll
        for (int s = 0; s < 9; ++s) {
            const int ky = s / 3, kx = s % 3;
            int p = (oyA + ky) * 10 + (oxA + kx);
            int offA = (p << 6) + ((g * 16) ^ ((p & 3) << 4));
            bf16x8s A = *(const bf16x8s*)((const char*)h2b + offA);
            bf16x8s B = *(const bf16x8s*)(w3e + (s * 16 + r16) * 32 + g * 8);
            acc = __builtin_amdgcn_mfma_f32_16x16x32_bf16(A, B, acc, 0, 0, 0);
        }
        // D: row (pixel-in-tile) = g*4+q, col (oc) = r16.  Stage into LDS tile.
        if (r16 < C3) {
            float bias = b3[e * C3 + r16];
            #pragma unroll
            for (int q = 0; q < 4; ++q) {
                int pxd = wave * 16 + g * 4 + q;
                int oyd = pxd >> 3, oxd = pxd & 7;
                outT[oyd * 3 + r16 / 3][oxd * 3 + r16 % 3] = acc[q] + bias;
            }
        }
    }
    __syncthreads();

    // ---- phase 4: coalesced output write: 24 rows x 6 float4 (96 B/row) ----
    if (t < 144) {
        int row = t / 6, c4 = t - row * 6;
        f32x4 v = *(const f32x4*)&outT[row][c4 * 4];
        int gr = R0 * 3 + row;              // 24*ty + row
        int gc = C0 * 3 + c4 * 4;           // 24*tx + 4*c4
        *(f32x4*)&out[(b * OUT_HW + gr) * OUT_HW + gc] = v;
    }
}

extern "C" void kernel_launch(void* const* d_in, const int* in_sizes, int n_in,
                              void* d_out, int out_size, void* d_ws, size_t ws_size,
                              hipStream_t stream) {
    const float* x  = (const float*)d_in[0];
    const int*   ci = (const int*)  d_in[1];
    const float* w1 = (const float*)d_in[2];
    const float* b1 = (const float*)d_in[3];
    const float* w2 = (const float*)d_in[4];
    const float* b2 = (const float*)d_in[5];
    const float* w3 = (const float*)d_in[6];
    const float* b3 = (const float*)d_in[7];
    float* out = (float*)d_out;

    {
        const int total = NE * C2 * C1 * 9 + NE * C1 * 32 + NE * 9 * 16 * 32;
        repack_weights_kernel<<<(total + 255) / 256, 256, 0, stream>>>(w1, w2, w3);
    }
    {
        dim3 grid(HW / 8, HW / 8, 32);
        espcn_fused_kernel<<<grid, 256, 0, stream>>>(x, ci, b1, b2, b3, out);
    }
}

// Round 8
// 247.060 us; speedup vs baseline: 2.1314x; 1.0104x over previous
//
#include <hip/hip_runtime.h>

#define NE 8
#define HW 128
#define OUT_HW 384
#define C1 64
#define C2 32
#define C3 9

typedef __attribute__((ext_vector_type(4))) float f32x4;
typedef __attribute__((ext_vector_type(8))) short bf16x8s;
typedef __attribute__((ext_vector_type(4))) unsigned short u16x4;

// Prepacked conv1 weights, bf16: [e][oc=64][tap=32 (25 valid, rest 0)]
__device__ __align__(16) unsigned short g_w1b[NE * C1 * 32];
// Prepacked conv2 weights, bf16: [e][koff(ky*3+kx)][oc=32][ic=64]
__device__ __align__(16) unsigned short g_w2b[NE * 9 * C2 * C1];
// Prepacked conv3 weights, bf16: [e][koff][oc=16 (9 valid)][ic=32]
__device__ __align__(16) unsigned short g_w3b[NE * 9 * 16 * 32];

__device__ __forceinline__ unsigned short f2bf(float f) {
    unsigned u = __builtin_bit_cast(unsigned, f);
    u += 0x7fffu + ((u >> 16) & 1u);          // round-nearest-even
    return (unsigned short)(u >> 16);
}

__global__ void repack_weights_kernel(const float* __restrict__ w1,
                                      const float* __restrict__ w2,
                                      const float* __restrict__ w3) {
    int i = blockIdx.x * 256 + threadIdx.x;
    const int n2 = NE * C2 * C1 * 9;          // 36864
    const int n1 = NE * C1 * 32;              // 16384
    const int n3 = NE * 9 * 16 * 32;          // 36864
    if (i < n2) {
        // source: [e][oc][ic][ky][kx] -> dest [e][koff][oc][ic]
        int e = i / (C2 * C1 * 9);
        int r = i - e * (C2 * C1 * 9);
        int oc = r / (C1 * 9); r -= oc * (C1 * 9);
        int ic = r / 9;
        int koff = r - ic * 9;
        g_w2b[((e * 9 + koff) * C2 + oc) * C1 + ic] = f2bf(w2[i]);
    } else if (i < n2 + n1) {
        int j = i - n2;                        // [e][oc][tap]
        int tap = j & 31;
        int eoc = j >> 5;                      // e*64+oc
        float v = (tap < 25) ? w1[eoc * 25 + tap] : 0.f;
        g_w1b[j] = f2bf(v);
    } else if (i < n2 + n1 + n3) {
        int j = i - n2 - n1;
        int e = j / (9 * 16 * 32);
        int r = j - e * (9 * 16 * 32);
        int koff = r / 512; r -= koff * 512;
        int oc = r / 32;
        int ic = r - oc * 32;
        float v = 0.f;
        if (oc < C3) v = w3[((e * C3 + oc) * 32 + ic) * 9 + koff];
        g_w3b[((e * 9 + koff) * 16 + oc) * 32 + ic] = f2bf(v);
    }
}

__device__ __forceinline__ float fast_tanh(float x) {
    float ax = fabsf(x);
    float ex = __expf(2.0f * ax);                       // inf-safe
    float tv = 1.0f - 2.0f * __builtin_amdgcn_rcpf(ex + 1.0f);
    return copysignf(tv, x);
}

__launch_bounds__(256, 4)
__global__ void espcn_fused_kernel(const float* __restrict__ x,
                                   const int* __restrict__ ci,
                                   const float* __restrict__ b1,
                                   const float* __restrict__ b2,
                                   const float* __restrict__ b3,
                                   float* __restrict__ out) {
    __shared__ float xs[16][17];                            // x patch
    __shared__ __align__(16) unsigned short imc[144 * 40];  // im2col [px][tap], 80B row stride
    __shared__ __align__(16) unsigned short h1s[144 * 64];  // [pixel][ic] bf16, XOR-swizzled (128B rows)
    __shared__ __align__(16) unsigned short h2b[100 * 32];  // [pixel][ic] bf16, XOR-swizzled (64B rows)
    // phase-3 output staging tile, aliased over h1s (dead by then): 24 x 28 floats
    float (*outT)[28] = (float(*)[28])h1s;                  // 2688 B << 18432 B

    const int tx = blockIdx.x, ty = blockIdx.y, b = blockIdx.z;
    const int R0 = ty * 8, C0 = tx * 8;
    int e = ci[b];
    e = __builtin_amdgcn_readfirstlane(e);                  // force SGPR: scalar weight loads
    const int t = threadIdx.x;
    const int lane = t & 63, wave = t >> 6;
    const int g = lane >> 4, r16 = lane & 15;

    // ---- phase 0: stage x patch rows [R0-4, R0+12), cols [C0-4, C0+12) ----
    {
        int i = t >> 4, j = t & 15;
        int gy = R0 - 4 + i, gx = C0 - 4 + j;
        float v = 0.f;
        if (gy >= 0 && gy < HW && gx >= 0 && gx < HW)
            v = x[(b * HW + gy) * HW + gx];
        xs[i][j] = v;
    }
    __syncthreads();

    // ---- phase 0.5: build im2col: 144 px x 16 tap-pairs (u32 writes) ----
    {
        #pragma unroll
        for (int q = 0; q < 9; ++q) {
            int idx = q * 256 + t;             // [0, 2304)
            int p = idx >> 4, w = idx & 15;
            int i = p / 12, j = p - i * 12;
            int tap0 = 2 * w, tap1 = 2 * w + 1;
            unsigned short lo = 0, hi = 0;
            if (tap0 < 25) lo = f2bf(xs[i + tap0 / 5][j + tap0 % 5]);
            if (tap1 < 25) hi = f2bf(xs[i + tap1 / 5][j + tap1 % 5]);
            *(unsigned*)((char*)imc + p * 80 + w * 4) = (unsigned)lo | ((unsigned)hi << 16);
        }
    }
    __syncthreads();

    // ---- phase 1: conv1 as MFMA, SWAPPED: M=oc(64, tile=wave), N=pixel(144), K=32 ----
    // D: col(lane)=pixel, rows=4 consecutive oc per thread -> packed b64 stores.
    {
        const unsigned short* w1e = g_w1b + e * C1 * 32;
        // A-frag (weights): lane holds row r16 (oc = wave*16+r16), k = g*8..g*8+7
        bf16x8s W = *(const bf16x8s*)(w1e + (wave * 16 + r16) * 32 + g * 8);
        const int oc0 = wave * 16 + g * 4;       // this thread's 4 D-rows (oc)
        f32x4 bias4 = *(const f32x4*)(b1 + e * C1 + oc0);
        #pragma unroll
        for (int mt = 0; mt < 9; ++mt) {
            // B-frag (im2col): lane holds col r16 (pixel = mt*16+r16), k = g*8..
            bf16x8s I = *(const bf16x8s*)((const char*)imc + (mt * 16 + r16) * 80 + g * 16);
            f32x4 acc = {0.f, 0.f, 0.f, 0.f};
            acc = __builtin_amdgcn_mfma_f32_16x16x32_bf16(W, I, acc, 0, 0, 0);
            int p = mt * 16 + r16;               // pixel this thread's 4 oc belong to
            int r = p / 12, jj = p - r * 12;
            int gy = R0 - 2 + r, gx = C0 - 2 + jj;
            bool in = (gy >= 0 && gy < HW && gx >= 0 && gx < HW);
            u16x4 hv;
            #pragma unroll
            for (int q = 0; q < 4; ++q)
                hv[q] = f2bf(in ? fast_tanh(acc[q] + bias4[q]) : 0.f);
            int off = (p << 7) + ((wave * 32 + g * 8) ^ ((p & 7) << 4));
            *(u16x4*)((char*)h1s + off) = hv;    // ds_write_b64
        }
    }
    __syncthreads();

    // ---- phase 2: conv2 as MFMA, SWAPPED: M=oc(32, 2 tiles), N=pixel(128 pad), K=576 ----
    {
        const unsigned short* w2e = g_w2b + e * 9 * C2 * C1;
        int ps0 = wave * 32 + r16;       if (ps0 > 99) ps0 = 99;
        int ps1 = wave * 32 + 16 + r16;  if (ps1 > 99) ps1 = 99;
        const int ab0 = (ps0 / 10) * 12 + (ps0 % 10);
        const int ab1 = (ps1 / 10) * 12 + (ps1 % 10);
        f32x4 acc00 = {0.f, 0.f, 0.f, 0.f}, acc01 = {0.f, 0.f, 0.f, 0.f};
        f32x4 acc10 = {0.f, 0.f, 0.f, 0.f}, acc11 = {0.f, 0.f, 0.f, 0.f};
        const int laneB = (r16 * C1 + g * 8);          // weight A-frag: row=oc=r16
        #pragma unroll
        for (int s = 0; s < 18; ++s) {
            const int koff = s >> 1;
            const int drow = (koff / 3) * 12 + (koff % 3);
            const int icoff2 = ((s & 1) * 32 + g * 8) * 2;
            int r0 = ab0 + drow, r1 = ab1 + drow;
            int o0 = ((r0 << 7) + icoff2) ^ ((r0 & 7) << 4);
            int o1 = ((r1 << 7) + icoff2) ^ ((r1 & 7) << 4);
            bf16x8s A0 = *(const bf16x8s*)((const char*)h1s + o0);   // h1 pixels (B-operand)
            bf16x8s A1 = *(const bf16x8s*)((const char*)h1s + o1);
            const unsigned short* wp = w2e + koff * C2 * C1 + (s & 1) * 32;
            bf16x8s B0 = *(const bf16x8s*)(wp + laneB);              // oc tile 0 (A-operand)
            bf16x8s B1 = *(const bf16x8s*)(wp + 16 * C1 + laneB);    // oc tile 1
            acc00 = __builtin_amdgcn_mfma_f32_16x16x32_bf16(B0, A0, acc00, 0, 0, 0);
            acc01 = __builtin_amdgcn_mfma_f32_16x16x32_bf16(B1, A0, acc01, 0, 0, 0);
            acc10 = __builtin_amdgcn_mfma_f32_16x16x32_bf16(B0, A1, acc10, 0, 0, 0);
            acc11 = __builtin_amdgcn_mfma_f32_16x16x32_bf16(B1, A1, acc11, 0, 0, 0);
        }
        // D: col=pixel (r16), rows=4 consecutive oc -> packed b64 stores per oc-tile.
        const float* b2e = b2 + e * C2;
        f32x4 bias0 = *(const f32x4*)(b2e + g * 4);
        f32x4 bias1 = *(const f32x4*)(b2e + 16 + g * 4);
        #pragma unroll
        for (int mm = 0; mm < 2; ++mm) {
            f32x4 a0 = mm ? acc10 : acc00;       // oc tile 0
            f32x4 a1 = mm ? acc11 : acc01;       // oc tile 1
            int pd = wave * 32 + mm * 16 + r16;
            if (pd < 100) {
                int y = pd / 10, xq2 = pd - y * 10;
                int gy = R0 - 1 + y, gx = C0 - 1 + xq2;
                bool in = (gy >= 0 && gy < HW && gx >= 0 && gx < HW);
                u16x4 h0, h1;
                #pragma unroll
                for (int q = 0; q < 4; ++q) {
                    h0[q] = f2bf(in ? fast_tanh(a0[q] + bias0[q]) : 0.f);
                    h1[q] = f2bf(in ? fast_tanh(a1[q] + bias1[q]) : 0.f);
                }
                int swz = (pd & 3) << 4;
                *(u16x4*)((char*)h2b + (pd << 6) + ((g * 8) ^ swz)) = h0;
                *(u16x4*)((char*)h2b + (pd << 6) + ((32 + g * 8) ^ swz)) = h1;
            }
        }
    }
    __syncthreads();

    // ---- phase 3: conv3 (3x3, 32->9 pad 16) as bf16 MFMA -> LDS out tile ----
    // M = 64 output pixels (4 tiles, one per wave), N = 16 (9 valid), K = 288 (9 steps).
    {
        const unsigned short* w3e = g_w3b + e * 9 * 16 * 32;
        const int pxA = wave * 16 + r16;            // A-row pixel
        const int oyA = pxA >> 3, oxA = pxA & 7;
        f32x4 acc = {0.f, 0.f, 0.f, 0.f};
        #pragma unroll
        for (int s = 0; s < 9; ++s) {
            const int ky = s / 3, kx = s % 3;
            int p = (oyA + ky) * 10 + (oxA + kx);
            int offA = (p << 6) + ((g * 16) ^ ((p & 3) << 4));
            bf16x8s A = *(const bf16x8s*)((const char*)h2b + offA);
            bf16x8s B = *(const bf16x8s*)(w3e + (s * 16 + r16) * 32 + g * 8);
            acc = __builtin_amdgcn_mfma_f32_16x16x32_bf16(A, B, acc, 0, 0, 0);
        }
        // D: row (pixel-in-tile) = g*4+q, col (oc) = r16.  Stage into LDS tile.
        if (r16 < C3) {
            float bias = b3[e * C3 + r16];
            #pragma unroll
            for (int q = 0; q < 4; ++q) {
                int pxd = wave * 16 + g * 4 + q;
                int oyd = pxd >> 3, oxd = pxd & 7;
                outT[oyd * 3 + r16 / 3][oxd * 3 + r16 % 3] = acc[q] + bias;
            }
        }
    }
    __syncthreads();

    // ---- phase 4: coalesced output write: 24 rows x 6 float4 (96 B/row) ----
    if (t < 144) {
        int row = t / 6, c4 = t - row * 6;
        f32x4 v = *(const f32x4*)&outT[row][c4 * 4];
        int gr = R0 * 3 + row;              // 24*ty + row
        int gc = C0 * 3 + c4 * 4;           // 24*tx + 4*c4
        *(f32x4*)&out[(b * OUT_HW + gr) * OUT_HW + gc] = v;
    }
}

extern "C" void kernel_launch(void* const* d_in, const int* in_sizes, int n_in,
                              void* d_out, int out_size, void* d_ws, size_t ws_size,
                              hipStream_t stream) {
    const float* x  = (const float*)d_in[0];
    const int*   ci = (const int*)  d_in[1];
    const float* w1 = (const float*)d_in[2];
    const float* b1 = (const float*)d_in[3];
    const float* w2 = (const float*)d_in[4];
    const float* b2 = (const float*)d_in[5];
    const float* w3 = (const float*)d_in[6];
    const float* b3 = (const float*)d_in[7];
    float* out = (float*)d_out;

    {
        const int total = NE * C2 * C1 * 9 + NE * C1 * 32 + NE * 9 * 16 * 32;
        repack_weights_kernel<<<(total + 255) / 256, 256, 0, stream>>>(w1, w2, w3);
    }
    {
        dim3 grid(HW / 8, HW / 8, 32);
        espcn_fused_kernel<<<grid, 256, 0, stream>>>(x, ci, b1, b2, b3, out);
    }
}